// Round 4
// baseline (87.072 us; speedup 1.0000x reference)
//
#include <hip/hip_runtime.h>
#include <hip/hip_bf16.h>
#include <cstddef>

// Problem constants: N=100000, E=1600000
constexpr int HID  = 128;
constexpr int OUTW = 32;    // N_CHUNKS * STRU
constexpr int TOT  = 64;    // P outs + Q outs (interleaved per node)
constexpr int STRU = 4;
constexpr int NCH  = 8;

typedef short  bf16x8 __attribute__((ext_vector_type(8)));
typedef float  f32x4  __attribute__((ext_vector_type(4)));
typedef int    int4v  __attribute__((ext_vector_type(4)));
typedef unsigned short u16x8 __attribute__((ext_vector_type(8)));

__device__ __forceinline__ unsigned short f2bf(float f) {
    unsigned u = __builtin_bit_cast(unsigned, f);
    u += 0x7FFFu + ((u >> 16) & 1u);          // round-to-nearest-even
    return (unsigned short)(u >> 16);
}

__device__ __forceinline__ float dot4(float4 a, float4 b) {
    return a.x * b.x + a.y * b.y + a.z * b.z + a.w * b.w;
}

// bf16 dot of 8 pairs packed in int4v words, accumulated into sum
__device__ __forceinline__ float bfdot(int4v a, int4v b, float sum) {
#pragma unroll
    for (int w = 0; w < 4; ++w) {
        float alo = __builtin_bit_cast(float, (unsigned)(a[w] << 16));
        float ahi = __builtin_bit_cast(float, (unsigned)a[w] & 0xffff0000u);
        float blo = __builtin_bit_cast(float, (unsigned)(b[w] << 16));
        float bhi = __builtin_bit_cast(float, (unsigned)b[w] & 0xffff0000u);
        sum = fmaf(alo, blo, sum);
        sum = fmaf(ahi, bhi, sum);
    }
    return sum;
}

// ---------------------------------------------------------------------------
// Prep: Wb[o][k] bf16 (o<32: Wq row o, o>=32: Wv row o-32), bias[o] fp32.
// ---------------------------------------------------------------------------
__global__ __launch_bounds__(256) void prep_bf16(
    const float* __restrict__ Wq, const float* __restrict__ bq,
    const float* __restrict__ Wv, const float* __restrict__ bv,
    unsigned short* __restrict__ Wb, float* __restrict__ bias)
{
    int tid = blockIdx.x * blockDim.x + threadIdx.x;
    if (tid < TOT * HID) {
        int o = tid >> 7, k = tid & 127;
        float w = (o < OUTW) ? Wq[o * HID + k] : Wv[(o - OUTW) * HID + k];
        Wb[tid] = f2bf(w);
    }
    if (tid < TOT) bias[tid] = (tid < OUTW) ? bq[tid] : bv[tid - OUTW];
}

// ---------------------------------------------------------------------------
// Proj (MFMA): per wave 16 nodes x 64 outputs, 4 tiles x 4 K-chunks of
// mfma_f32_16x16x32_bf16. Epilogue: LDS transpose (pad +8 shorts -> <=2-way
// bank aliasing, free) then fully coalesced 16B global stores into the
// interleaved PQ[node][64] buffer (P = cols 0..31, Q = cols 32..63).
// ---------------------------------------------------------------------------
__global__ __launch_bounds__(256) void proj_mfma(
    const float* __restrict__ x,
    const unsigned short* __restrict__ Wb,
    const float* __restrict__ bias,
    unsigned short* __restrict__ PQ,
    int n_nodes)
{
    __shared__ unsigned short sPQ[64][TOT + 8];   // 64 nodes x 64 cols, pad 8

    const int wid  = threadIdx.x >> 6;
    const int lane = threadIdx.x & 63;
    const int lr   = lane & 15;   // A-row / B-col / C-col
    const int lg   = lane >> 4;   // k-group / C row-group
    const int base = blockIdx.x * 64;
    const int m0   = base + wid * 16;

    // B fragments: 4 output tiles x 4 K-chunks (64 VGPRs total)
    bf16x8 bfrag[4][4];
#pragma unroll
    for (int t = 0; t < 4; ++t)
#pragma unroll
        for (int kc = 0; kc < 4; ++kc)
            bfrag[t][kc] = *reinterpret_cast<const bf16x8*>(
                Wb + ((size_t)(t * 16 + lr) * HID + kc * 32 + lg * 8));

    f32x4 acc[4];
#pragma unroll
    for (int t = 0; t < 4; ++t) {
        float b = bias[t * 16 + lr];
        acc[t][0] = b; acc[t][1] = b; acc[t][2] = b; acc[t][3] = b;
    }

    const int  arow = m0 + lr;
    const bool aok  = arow < n_nodes;
    const float* ap = x + (size_t)arow * HID;

#pragma unroll
    for (int kc = 0; kc < 4; ++kc) {
        float4 f0 = make_float4(0.f, 0.f, 0.f, 0.f), f1 = f0;
        if (aok) {
            const float4* p = reinterpret_cast<const float4*>(ap + kc * 32 + lg * 8);
            f0 = p[0]; f1 = p[1];
        }
        bf16x8 a;
        a[0] = (short)f2bf(f0.x); a[1] = (short)f2bf(f0.y);
        a[2] = (short)f2bf(f0.z); a[3] = (short)f2bf(f0.w);
        a[4] = (short)f2bf(f1.x); a[5] = (short)f2bf(f1.y);
        a[6] = (short)f2bf(f1.z); a[7] = (short)f2bf(f1.w);
#pragma unroll
        for (int t = 0; t < 4; ++t)
            acc[t] = __builtin_amdgcn_mfma_f32_16x16x32_bf16(a, bfrag[t][kc], acc[t], 0, 0, 0);
    }

    // ---- epilogue: fragments -> LDS ----
    const int lrow = wid * 16 + lg * 4;
#pragma unroll
    for (int t = 0; t < 4; ++t)
#pragma unroll
        for (int j = 0; j < 4; ++j)
            sPQ[lrow + j][t * 16 + lr] = f2bf(acc[t][j]);
    __syncthreads();

    // ---- LDS -> global, coalesced: 4 threads per node row, 32B each ----
    const int row  = threadIdx.x >> 2;          // 0..63
    const int cseg = (threadIdx.x & 3) * 16;    // 0,16,32,48
    const int node = base + row;
    if (node < n_nodes) {
        u16x8 v0 = *reinterpret_cast<const u16x8*>(&sPQ[row][cseg]);
        u16x8 v1 = *reinterpret_cast<const u16x8*>(&sPQ[row][cseg + 8]);
        u16x8* dst = reinterpret_cast<u16x8*>(PQ + (size_t)node * TOT + cseg);
        dst[0] = v0;
        dst[1] = v1;
    }
}

// ---------------------------------------------------------------------------
// Edge: 2 edges per thread. Gather P from PQ[e0][0..31], Q from PQ[e1][32..63],
// chunk-dot in fp32, sigmoid, coalesced float2 stores.
// ---------------------------------------------------------------------------
__global__ __launch_bounds__(256) void edge_bf16(
    const int* __restrict__ e,
    const unsigned short* __restrict__ PQ,
    const float* __restrict__ ratio_p,
    float* __restrict__ out, int E_)
{
    int i = (blockIdx.x * blockDim.x + threadIdx.x) * 2;
    if (i >= E_) return;

    float scale = (1.0f - ratio_p[0]) * 0.5f;
    const bool two = (i + 1 < E_);

    int e0a, e0b, e1a, e1b;
    if (two) {
        int2 ea = *reinterpret_cast<const int2*>(e + i);
        int2 eb = *reinterpret_cast<const int2*>(e + E_ + i);
        e0a = ea.x; e0b = ea.y; e1a = eb.x; e1b = eb.y;
    } else {
        e0a = e0b = e[i];
        e1a = e1b = e[E_ + i];
    }

    const int4v* pA = reinterpret_cast<const int4v*>(PQ + (size_t)e0a * TOT);
    const int4v* pB = reinterpret_cast<const int4v*>(PQ + (size_t)e0b * TOT);
    const int4v* qA = reinterpret_cast<const int4v*>(PQ + (size_t)e1a * TOT + OUTW);
    const int4v* qB = reinterpret_cast<const int4v*>(PQ + (size_t)e1b * TOT + OUTW);

    int4v a0[STRU], b0[STRU], a1[STRU], b1[STRU];
#pragma unroll
    for (int s = 0; s < STRU; ++s) {
        a0[s] = pA[s];
        b0[s] = qA[s];
        a1[s] = pB[s];
        b1[s] = qB[s];
    }

#pragma unroll
    for (int s = 0; s < STRU; ++s) {
        float s0 = bfdot(a0[s], b0[s], 0.f);
        float s1 = bfdot(a1[s], b1[s], 0.f);
        float r0 = 1.0f / (1.0f + __expf(-s0)) * scale + 1.0f;
        float r1 = 1.0f / (1.0f + __expf(-s1)) * scale + 1.0f;
        if (two) {
            *reinterpret_cast<float2*>(out + (size_t)s * E_ + i) = make_float2(r0, r1);
        } else {
            out[(size_t)s * E_ + i] = r0;
        }
    }
}

// ---------------------------------------------------------------------------
// Fallback: fully fused per-edge (only if workspace too small).
// ---------------------------------------------------------------------------
__global__ __launch_bounds__(256) void fused_kernel(
    const float* __restrict__ x,
    const int* __restrict__ e,
    const float* __restrict__ ratio_p,
    const float* __restrict__ Wq, const float* __restrict__ bq,
    const float* __restrict__ Wv, const float* __restrict__ bv,
    float* __restrict__ out, int E_)
{
    int i = blockIdx.x * blockDim.x + threadIdx.x;
    if (i >= E_) return;

    float scale = (1.0f - ratio_p[0]) * 0.5f;
    int e0 = e[i];
    int e1 = e[E_ + i];

    const float4* __restrict__ xu  = reinterpret_cast<const float4*>(x + (size_t)e0 * HID);
    const float4* __restrict__ xv_ = reinterpret_cast<const float4*>(x + (size_t)e1 * HID);
    const float4* __restrict__ Wq4 = reinterpret_cast<const float4*>(Wq);
    const float4* __restrict__ Wv4 = reinterpret_cast<const float4*>(Wv);

#pragma unroll 1
    for (int s = 0; s < STRU; ++s) {
        float accP[NCH], accQ[NCH];
#pragma unroll
        for (int c = 0; c < NCH; ++c) { accP[c] = bq[s*NCH+c]; accQ[c] = bv[s*NCH+c]; }
        for (int kc = 0; kc < HID / 4; ++kc) {
            float4 u = xu[kc];
            float4 v = xv_[kc];
#pragma unroll
            for (int c = 0; c < NCH; ++c) {
                int o = s * NCH + c;
                accP[c] += dot4(u, Wq4[o * (HID / 4) + kc]);
                accQ[c] += dot4(v, Wv4[o * (HID / 4) + kc]);
            }
        }
        float sum = 0.0f;
#pragma unroll
        for (int c = 0; c < NCH; ++c) sum += accP[c] * accQ[c];
        float sig = 1.0f / (1.0f + __expf(-sum));
        out[(size_t)s * E_ + i] = sig * scale + 1.0f;
    }
}

extern "C" void kernel_launch(void* const* d_in, const int* in_sizes, int n_in,
                              void* d_out, int out_size, void* d_ws, size_t ws_size,
                              hipStream_t stream)
{
    const float* x     = (const float*)d_in[0];
    const int*   e     = (const int*)  d_in[1];
    const float* ratio = (const float*)d_in[2];
    const float* Wq    = (const float*)d_in[3];
    const float* bq    = (const float*)d_in[4];
    const float* Wv    = (const float*)d_in[5];
    const float* bv    = (const float*)d_in[6];
    float* out = (float*)d_out;

    int N_ = in_sizes[0] / HID;
    int E_ = in_sizes[1] / 2;

    // workspace: PQ (bf16 N_*64) | Wb (bf16 64*128) | bias (f32 64)
    size_t need = (size_t)N_ * TOT * sizeof(unsigned short)
                + (size_t)TOT * HID * sizeof(unsigned short)
                + TOT * sizeof(float);
    if (ws_size >= need) {
        unsigned short* PQ   = (unsigned short*)d_ws;
        unsigned short* Wb   = PQ + (size_t)N_ * TOT;
        float*          bias = (float*)(Wb + (size_t)TOT * HID);

        prep_bf16<<<(TOT * HID + 255) / 256, 256, 0, stream>>>(Wq, bq, Wv, bv, Wb, bias);
        proj_mfma<<<(N_ + 63) / 64, 256, 0, stream>>>(x, Wb, bias, PQ, N_);
        int nthread = (E_ + 1) / 2;
        edge_bf16<<<(nthread + 255) / 256, 256, 0, stream>>>(e, PQ, ratio, out, E_);
    } else {
        fused_kernel<<<(E_ + 255) / 256, 256, 0, stream>>>(x, e, ratio, Wq, bq, Wv, bv, out, E_);
    }
}

// Round 5
// 84.607 us; speedup vs baseline: 1.0291x; 1.0291x over previous
//
#include <hip/hip_runtime.h>
#include <hip/hip_bf16.h>
#include <cstddef>

// Problem constants: N=100000, E=1600000
constexpr int HID  = 128;
constexpr int OUTW = 32;    // N_CHUNKS * STRU
constexpr int TOT  = 64;    // P outs + Q outs
constexpr int STRU = 4;
constexpr int NCH  = 8;

typedef short  bf16x8 __attribute__((ext_vector_type(8)));
typedef float  f32x4  __attribute__((ext_vector_type(4)));
typedef int    int4v  __attribute__((ext_vector_type(4)));
typedef unsigned short u16x8 __attribute__((ext_vector_type(8)));

__device__ __forceinline__ unsigned short f2bf(float f) {
    unsigned u = __builtin_bit_cast(unsigned, f);
    u += 0x7FFFu + ((u >> 16) & 1u);          // round-to-nearest-even
    return (unsigned short)(u >> 16);
}

__device__ __forceinline__ float dot4(float4 a, float4 b) {
    return a.x * b.x + a.y * b.y + a.z * b.z + a.w * b.w;
}

// bf16 dot of 8 pairs packed in int4v words, accumulated into sum
__device__ __forceinline__ float bfdot(int4v a, int4v b, float sum) {
#pragma unroll
    for (int w = 0; w < 4; ++w) {
        float alo = __builtin_bit_cast(float, (unsigned)(a[w] << 16));
        float ahi = __builtin_bit_cast(float, (unsigned)a[w] & 0xffff0000u);
        float blo = __builtin_bit_cast(float, (unsigned)(b[w] << 16));
        float bhi = __builtin_bit_cast(float, (unsigned)b[w] & 0xffff0000u);
        sum = fmaf(alo, blo, sum);
        sum = fmaf(ahi, bhi, sum);
    }
    return sum;
}

// ---------------------------------------------------------------------------
// Prep: Wb[o][k] bf16 (o<32: Wq row o, o>=32: Wv row o-32), bias[o] fp32.
// ---------------------------------------------------------------------------
__global__ __launch_bounds__(256) void prep_bf16(
    const float* __restrict__ Wq, const float* __restrict__ bq,
    const float* __restrict__ Wv, const float* __restrict__ bv,
    unsigned short* __restrict__ Wb, float* __restrict__ bias)
{
    int tid = blockIdx.x * blockDim.x + threadIdx.x;
    if (tid < TOT * HID) {
        int o = tid >> 7, k = tid & 127;
        float w = (o < OUTW) ? Wq[o * HID + k] : Wv[(o - OUTW) * HID + k];
        Wb[tid] = f2bf(w);
    }
    if (tid < TOT) bias[tid] = (tid < OUTW) ? bq[tid] : bv[tid - OUTW];
}

// ---------------------------------------------------------------------------
// Proj (MFMA): per wave 16 nodes x 64 outputs, 4 tiles x 4 K-chunks of
// mfma_f32_16x16x32_bf16. x loads issued FIRST (nt, streaming) for MLP;
// epilogue transposes fragments through padded LDS and writes P/Q with
// fully coalesced 16B stores.
// ---------------------------------------------------------------------------
__global__ __launch_bounds__(256) void proj_mfma(
    const float* __restrict__ x,
    const unsigned short* __restrict__ Wb,
    const float* __restrict__ bias,
    unsigned short* __restrict__ P,
    unsigned short* __restrict__ Q,
    int n_nodes)
{
    __shared__ unsigned short sPQ[64][TOT + 8];   // 64 nodes x 64 cols, pad 8

    const int wid  = threadIdx.x >> 6;
    const int lane = threadIdx.x & 63;
    const int lr   = lane & 15;   // A-row / B-col / C-col
    const int lg   = lane >> 4;   // k-group / C row-group
    const int base = blockIdx.x * 64;
    const int m0   = base + wid * 16;

    // ---- issue all x loads first (streaming -> nt) ----
    const int  arow = m0 + lr;
    const bool aok  = arow < n_nodes;
    const float* ap = x + (size_t)arow * HID;

    f32x4 xv[8];
#pragma unroll
    for (int kc = 0; kc < 4; ++kc) {
        if (aok) {
            const f32x4* p = reinterpret_cast<const f32x4*>(ap + kc * 32 + lg * 8);
            xv[2 * kc + 0] = __builtin_nontemporal_load(p);
            xv[2 * kc + 1] = __builtin_nontemporal_load(p + 1);
        } else {
            xv[2 * kc + 0] = (f32x4)0.f;
            xv[2 * kc + 1] = (f32x4)0.f;
        }
    }

    // ---- B fragments: 4 output tiles x 4 K-chunks (L2-resident) ----
    bf16x8 bfrag[4][4];
#pragma unroll
    for (int t = 0; t < 4; ++t)
#pragma unroll
        for (int kc = 0; kc < 4; ++kc)
            bfrag[t][kc] = *reinterpret_cast<const bf16x8*>(
                Wb + ((size_t)(t * 16 + lr) * HID + kc * 32 + lg * 8));

    f32x4 acc[4];
#pragma unroll
    for (int t = 0; t < 4; ++t) {
        float b = bias[t * 16 + lr];
        acc[t][0] = b; acc[t][1] = b; acc[t][2] = b; acc[t][3] = b;
    }

#pragma unroll
    for (int kc = 0; kc < 4; ++kc) {
        f32x4 f0 = xv[2 * kc + 0], f1 = xv[2 * kc + 1];
        bf16x8 a;
        a[0] = (short)f2bf(f0[0]); a[1] = (short)f2bf(f0[1]);
        a[2] = (short)f2bf(f0[2]); a[3] = (short)f2bf(f0[3]);
        a[4] = (short)f2bf(f1[0]); a[5] = (short)f2bf(f1[1]);
        a[6] = (short)f2bf(f1[2]); a[7] = (short)f2bf(f1[3]);
#pragma unroll
        for (int t = 0; t < 4; ++t)
            acc[t] = __builtin_amdgcn_mfma_f32_16x16x32_bf16(a, bfrag[t][kc], acc[t], 0, 0, 0);
    }

    // ---- epilogue: fragments -> LDS (2B stores, <=2-way bank alias: free) ----
    const int lrow = wid * 16 + lg * 4;
#pragma unroll
    for (int t = 0; t < 4; ++t)
#pragma unroll
        for (int j = 0; j < 4; ++j)
            sPQ[lrow + j][t * 16 + lr] = f2bf(acc[t][j]);
    __syncthreads();

    // ---- LDS -> global, coalesced: 4 threads/node, 32B each ----
    const int row  = threadIdx.x >> 2;      // 0..63
    const int q    = threadIdx.x & 3;       // 0,1 -> P halves; 2,3 -> Q halves
    const int node = base + row;
    if (node < n_nodes) {
        const int scol = q * 16;            // 0,16,32,48
        u16x8 v0 = *reinterpret_cast<const u16x8*>(&sPQ[row][scol]);
        u16x8 v1 = *reinterpret_cast<const u16x8*>(&sPQ[row][scol + 8]);
        unsigned short* dstbase = (q < 2) ? (P + (size_t)node * OUTW + q * 16)
                                          : (Q + (size_t)node * OUTW + (q - 2) * 16);
        u16x8* dst = reinterpret_cast<u16x8*>(dstbase);
        dst[0] = v0;
        dst[1] = v1;
    }
}

// ---------------------------------------------------------------------------
// Edge: 1 edge/thread (proven best MLP). Gather bf16 P[e0], Q[e1] (64B rows),
// chunk-dot in fp32, sigmoid. Index loads + out stores are non-temporal so
// they don't evict the P/Q gather working set from L2.
// ---------------------------------------------------------------------------
__global__ __launch_bounds__(256) void edge_bf16(
    const int* __restrict__ e,
    const unsigned short* __restrict__ P,
    const unsigned short* __restrict__ Q,
    const float* __restrict__ ratio_p,
    float* __restrict__ out, int E_)
{
    int i = blockIdx.x * blockDim.x + threadIdx.x;
    if (i >= E_) return;

    float scale = (1.0f - ratio_p[0]) * 0.5f;
    int e0 = __builtin_nontemporal_load(e + i);
    int e1 = __builtin_nontemporal_load(e + E_ + i);

    const int4v* p4 = reinterpret_cast<const int4v*>(P + (size_t)e0 * OUTW);
    const int4v* q4 = reinterpret_cast<const int4v*>(Q + (size_t)e1 * OUTW);

    int4v a[STRU], b[STRU];
#pragma unroll
    for (int s = 0; s < STRU; ++s) { a[s] = p4[s]; b[s] = q4[s]; }

#pragma unroll
    for (int s = 0; s < STRU; ++s) {
        float sum = bfdot(a[s], b[s], 0.f);
        float sig = 1.0f / (1.0f + __expf(-sum));
        float r   = sig * scale + 1.0f;
        __builtin_nontemporal_store(r, out + (size_t)s * E_ + i);
    }
}

// ---------------------------------------------------------------------------
// Fallback: fully fused per-edge (only if workspace too small).
// ---------------------------------------------------------------------------
__global__ __launch_bounds__(256) void fused_kernel(
    const float* __restrict__ x,
    const int* __restrict__ e,
    const float* __restrict__ ratio_p,
    const float* __restrict__ Wq, const float* __restrict__ bq,
    const float* __restrict__ Wv, const float* __restrict__ bv,
    float* __restrict__ out, int E_)
{
    int i = blockIdx.x * blockDim.x + threadIdx.x;
    if (i >= E_) return;

    float scale = (1.0f - ratio_p[0]) * 0.5f;
    int e0 = e[i];
    int e1 = e[E_ + i];

    const float4* __restrict__ xu  = reinterpret_cast<const float4*>(x + (size_t)e0 * HID);
    const float4* __restrict__ xv_ = reinterpret_cast<const float4*>(x + (size_t)e1 * HID);
    const float4* __restrict__ Wq4 = reinterpret_cast<const float4*>(Wq);
    const float4* __restrict__ Wv4 = reinterpret_cast<const float4*>(Wv);

#pragma unroll 1
    for (int s = 0; s < STRU; ++s) {
        float accP[NCH], accQ[NCH];
#pragma unroll
        for (int c = 0; c < NCH; ++c) { accP[c] = bq[s*NCH+c]; accQ[c] = bv[s*NCH+c]; }
        for (int kc = 0; kc < HID / 4; ++kc) {
            float4 u = xu[kc];
            float4 v = xv_[kc];
#pragma unroll
            for (int c = 0; c < NCH; ++c) {
                int o = s * NCH + c;
                accP[c] += dot4(u, Wq4[o * (HID / 4) + kc]);
                accQ[c] += dot4(v, Wv4[o * (HID / 4) + kc]);
            }
        }
        float sum = 0.0f;
#pragma unroll
        for (int c = 0; c < NCH; ++c) sum += accP[c] * accQ[c];
        float sig = 1.0f / (1.0f + __expf(-sum));
        out[(size_t)s * E_ + i] = sig * scale + 1.0f;
    }
}

extern "C" void kernel_launch(void* const* d_in, const int* in_sizes, int n_in,
                              void* d_out, int out_size, void* d_ws, size_t ws_size,
                              hipStream_t stream)
{
    const float* x     = (const float*)d_in[0];
    const int*   e     = (const int*)  d_in[1];
    const float* ratio = (const float*)d_in[2];
    const float* Wq    = (const float*)d_in[3];
    const float* bq    = (const float*)d_in[4];
    const float* Wv    = (const float*)d_in[5];
    const float* bv    = (const float*)d_in[6];
    float* out = (float*)d_out;

    int N_ = in_sizes[0] / HID;
    int E_ = in_sizes[1] / 2;

    // workspace: P (bf16 N_*32) | Q (bf16 N_*32) | Wb (bf16 64*128) | bias (f32 64)
    size_t need = (size_t)N_ * OUTW * 2 * sizeof(unsigned short)
                + (size_t)TOT * HID * sizeof(unsigned short)
                + TOT * sizeof(float);
    if (ws_size >= need) {
        unsigned short* P    = (unsigned short*)d_ws;
        unsigned short* Qb   = P + (size_t)N_ * OUTW;
        unsigned short* Wb   = Qb + (size_t)N_ * OUTW;
        float*          bias = (float*)(Wb + (size_t)TOT * HID);

        prep_bf16<<<(TOT * HID + 255) / 256, 256, 0, stream>>>(Wq, bq, Wv, bv, Wb, bias);
        proj_mfma<<<(N_ + 63) / 64, 256, 0, stream>>>(x, Wb, bias, P, Qb, N_);
        edge_bf16<<<(E_ + 255) / 256, 256, 0, stream>>>(e, P, Qb, ratio, out, E_);
    } else {
        fused_kernel<<<(E_ + 255) / 256, 256, 0, stream>>>(x, e, ratio, Wq, bq, Wv, bv, out, E_);
    }
}

// Round 6
// 68.414 us; speedup vs baseline: 1.2727x; 1.2367x over previous
//
#include <hip/hip_runtime.h>
#include <hip/hip_bf16.h>
#include <cstddef>

// Problem constants: N=100000, E=1600000
constexpr int HID  = 128;
constexpr int OUTW = 32;    // N_CHUNKS * STRU
constexpr int TOT  = 64;    // P outs + Q outs
constexpr int STRU = 4;
constexpr int NCH  = 8;

typedef short  bf16x8 __attribute__((ext_vector_type(8)));
typedef float  f32x4  __attribute__((ext_vector_type(4)));
typedef int    int4v  __attribute__((ext_vector_type(4)));
typedef unsigned short u16x8 __attribute__((ext_vector_type(8)));

__device__ __forceinline__ unsigned short f2bf(float f) {
    unsigned u = __builtin_bit_cast(unsigned, f);
    u += 0x7FFFu + ((u >> 16) & 1u);          // round-to-nearest-even
    return (unsigned short)(u >> 16);
}

__device__ __forceinline__ float dot4(float4 a, float4 b) {
    return a.x * b.x + a.y * b.y + a.z * b.z + a.w * b.w;
}

// bf16 dot of 8 pairs packed in int4v words, accumulated into sum
__device__ __forceinline__ float bfdot(int4v a, int4v b, float sum) {
#pragma unroll
    for (int w = 0; w < 4; ++w) {
        float alo = __builtin_bit_cast(float, (unsigned)(a[w] << 16));
        float ahi = __builtin_bit_cast(float, (unsigned)a[w] & 0xffff0000u);
        float blo = __builtin_bit_cast(float, (unsigned)(b[w] << 16));
        float bhi = __builtin_bit_cast(float, (unsigned)b[w] & 0xffff0000u);
        sum = fmaf(alo, blo, sum);
        sum = fmaf(ahi, bhi, sum);
    }
    return sum;
}

// ---------------------------------------------------------------------------
// Prep: Wfrag in MFMA fragment order. Element ((t*4+kc)*64 + lane)*8 + j
//   = W_row(o)[k], o = t*16 + (lane&15), k = kc*32 + (lane>>4)*8 + j,
//   o<32 -> Wq row o, o>=32 -> Wv row o-32. bias[o] fp32.
// ---------------------------------------------------------------------------
__global__ __launch_bounds__(256) void prep_bf16(
    const float* __restrict__ Wq, const float* __restrict__ bq,
    const float* __restrict__ Wv, const float* __restrict__ bv,
    unsigned short* __restrict__ Wfrag, float* __restrict__ bias)
{
    int tid = blockIdx.x * blockDim.x + threadIdx.x;
    if (tid < TOT * HID) {
        int j    = tid & 7;
        int lane = (tid >> 3) & 63;
        int kc   = (tid >> 9) & 3;
        int t    = tid >> 11;
        int o = t * 16 + (lane & 15);
        int k = kc * 32 + (lane >> 4) * 8 + j;
        float w = (o < OUTW) ? Wq[o * HID + k] : Wv[(o - OUTW) * HID + k];
        Wfrag[tid] = f2bf(w);
    }
    if (tid < TOT) bias[tid] = (tid < OUTW) ? bq[tid] : bv[tid - OUTW];
}

// ---------------------------------------------------------------------------
// Proj (MFMA): per wave 16 nodes x 64 outputs, 4 tiles x 4 K-chunks of
// mfma_f32_16x16x32_bf16. Weights staged in LDS (fragment-ordered ->
// stride-16B conflict-free ds_read_b128, short live ranges -> low VGPR,
// high occupancy). Epilogue: padded-LDS transpose, coalesced 16B stores.
// ---------------------------------------------------------------------------
__global__ __launch_bounds__(256) void proj_mfma(
    const float* __restrict__ x,
    const unsigned short* __restrict__ Wfrag,
    const float* __restrict__ bias,
    unsigned short* __restrict__ P,
    unsigned short* __restrict__ Q,
    int n_nodes)
{
    __shared__ unsigned short sW[16 * 64 * 8];    // 16 KB, fragment-ordered
    __shared__ unsigned short sPQ[64][TOT + 8];   // 9.2 KB transpose buffer

    const int tid  = threadIdx.x;
    const int wid  = tid >> 6;
    const int lane = tid & 63;
    const int lr   = lane & 15;   // A-row / C-col
    const int lg   = lane >> 4;   // k-group / C row-group
    const int base = blockIdx.x * 64;
    const int m0   = base + wid * 16;

    // ---- issue all x loads first ----
    const int  arow = m0 + lr;
    const bool aok  = arow < n_nodes;
    const float* ap = x + (size_t)arow * HID;

    f32x4 xv[8];
#pragma unroll
    for (int kc = 0; kc < 4; ++kc) {
        if (aok) {
            const f32x4* p = reinterpret_cast<const f32x4*>(ap + kc * 32 + lg * 8);
            xv[2 * kc + 0] = p[0];
            xv[2 * kc + 1] = p[1];
        } else {
            xv[2 * kc + 0] = (f32x4)0.f;
            xv[2 * kc + 1] = (f32x4)0.f;
        }
    }

    // ---- stage weights to LDS: 16 KB = 4 coalesced dwordx4 per thread ----
    {
        const int4v* src = reinterpret_cast<const int4v*>(Wfrag);
        int4v*       dst = reinterpret_cast<int4v*>(sW);
#pragma unroll
        for (int j = 0; j < 4; ++j)
            dst[tid + 256 * j] = src[tid + 256 * j];
    }

    f32x4 acc[4];
#pragma unroll
    for (int t = 0; t < 4; ++t) {
        float b = bias[t * 16 + lr];
        acc[t][0] = b; acc[t][1] = b; acc[t][2] = b; acc[t][3] = b;
    }

    __syncthreads();

#pragma unroll
    for (int kc = 0; kc < 4; ++kc) {
        f32x4 f0 = xv[2 * kc + 0], f1 = xv[2 * kc + 1];
        bf16x8 a;
        a[0] = (short)f2bf(f0[0]); a[1] = (short)f2bf(f0[1]);
        a[2] = (short)f2bf(f0[2]); a[3] = (short)f2bf(f0[3]);
        a[4] = (short)f2bf(f1[0]); a[5] = (short)f2bf(f1[1]);
        a[6] = (short)f2bf(f1[2]); a[7] = (short)f2bf(f1[3]);
#pragma unroll
        for (int t = 0; t < 4; ++t) {
            bf16x8 bf = *reinterpret_cast<const bf16x8*>(sW + ((size_t)(t * 4 + kc) * 64 + lane) * 8);
            acc[t] = __builtin_amdgcn_mfma_f32_16x16x32_bf16(a, bf, acc[t], 0, 0, 0);
        }
    }

    // ---- epilogue: fragments -> LDS (2B stores, <=2-way alias: free) ----
    const int lrow = wid * 16 + lg * 4;
#pragma unroll
    for (int t = 0; t < 4; ++t)
#pragma unroll
        for (int j = 0; j < 4; ++j)
            sPQ[lrow + j][t * 16 + lr] = f2bf(acc[t][j]);
    __syncthreads();

    // ---- LDS -> global, coalesced: 4 threads/node, 32B each ----
    const int row  = tid >> 2;          // 0..63
    const int q    = tid & 3;           // 0,1 -> P halves; 2,3 -> Q halves
    const int node = base + row;
    if (node < n_nodes) {
        const int scol = q * 16;        // 0,16,32,48
        u16x8 v0 = *reinterpret_cast<const u16x8*>(&sPQ[row][scol]);
        u16x8 v1 = *reinterpret_cast<const u16x8*>(&sPQ[row][scol + 8]);
        unsigned short* dstbase = (q < 2) ? (P + (size_t)node * OUTW + q * 16)
                                          : (Q + (size_t)node * OUTW + (q - 2) * 16);
        u16x8* dst = reinterpret_cast<u16x8*>(dstbase);
        dst[0] = v0;
        dst[1] = v1;
    }
}

// ---------------------------------------------------------------------------
// Edge: 1 edge/thread (proven best). Gather bf16 P[e0], Q[e1] (64B rows),
// chunk-dot in fp32, sigmoid. nt on index loads + out stores so they don't
// evict the P/Q gather working set from L2.
// ---------------------------------------------------------------------------
__global__ __launch_bounds__(256) void edge_bf16(
    const int* __restrict__ e,
    const unsigned short* __restrict__ P,
    const unsigned short* __restrict__ Q,
    const float* __restrict__ ratio_p,
    float* __restrict__ out, int E_)
{
    int i = blockIdx.x * blockDim.x + threadIdx.x;
    if (i >= E_) return;

    float scale = (1.0f - ratio_p[0]) * 0.5f;
    int e0 = __builtin_nontemporal_load(e + i);
    int e1 = __builtin_nontemporal_load(e + E_ + i);

    const int4v* p4 = reinterpret_cast<const int4v*>(P + (size_t)e0 * OUTW);
    const int4v* q4 = reinterpret_cast<const int4v*>(Q + (size_t)e1 * OUTW);

    int4v a[STRU], b[STRU];
#pragma unroll
    for (int s = 0; s < STRU; ++s) { a[s] = p4[s]; b[s] = q4[s]; }

#pragma unroll
    for (int s = 0; s < STRU; ++s) {
        float sum = bfdot(a[s], b[s], 0.f);
        float sig = 1.0f / (1.0f + __expf(-sum));
        float r   = sig * scale + 1.0f;
        __builtin_nontemporal_store(r, out + (size_t)s * E_ + i);
    }
}

// ---------------------------------------------------------------------------
// Fallback: fully fused per-edge (only if workspace too small).
// ---------------------------------------------------------------------------
__global__ __launch_bounds__(256) void fused_kernel(
    const float* __restrict__ x,
    const int* __restrict__ e,
    const float* __restrict__ ratio_p,
    const float* __restrict__ Wq, const float* __restrict__ bq,
    const float* __restrict__ Wv, const float* __restrict__ bv,
    float* __restrict__ out, int E_)
{
    int i = blockIdx.x * blockDim.x + threadIdx.x;
    if (i >= E_) return;

    float scale = (1.0f - ratio_p[0]) * 0.5f;
    int e0 = e[i];
    int e1 = e[E_ + i];

    const float4* __restrict__ xu  = reinterpret_cast<const float4*>(x + (size_t)e0 * HID);
    const float4* __restrict__ xv_ = reinterpret_cast<const float4*>(x + (size_t)e1 * HID);
    const float4* __restrict__ Wq4 = reinterpret_cast<const float4*>(Wq);
    const float4* __restrict__ Wv4 = reinterpret_cast<const float4*>(Wv);

#pragma unroll 1
    for (int s = 0; s < STRU; ++s) {
        float accP[NCH], accQ[NCH];
#pragma unroll
        for (int c = 0; c < NCH; ++c) { accP[c] = bq[s*NCH+c]; accQ[c] = bv[s*NCH+c]; }
        for (int kc = 0; kc < HID / 4; ++kc) {
            float4 u = xu[kc];
            float4 v = xv_[kc];
#pragma unroll
            for (int c = 0; c < NCH; ++c) {
                int o = s * NCH + c;
                accP[c] += dot4(u, Wq4[o * (HID / 4) + kc]);
                accQ[c] += dot4(v, Wv4[o * (HID / 4) + kc]);
            }
        }
        float sum = 0.0f;
#pragma unroll
        for (int c = 0; c < NCH; ++c) sum += accP[c] * accQ[c];
        float sig = 1.0f / (1.0f + __expf(-sum));
        out[(size_t)s * E_ + i] = sig * scale + 1.0f;
    }
}

extern "C" void kernel_launch(void* const* d_in, const int* in_sizes, int n_in,
                              void* d_out, int out_size, void* d_ws, size_t ws_size,
                              hipStream_t stream)
{
    const float* x     = (const float*)d_in[0];
    const int*   e     = (const int*)  d_in[1];
    const float* ratio = (const float*)d_in[2];
    const float* Wq    = (const float*)d_in[3];
    const float* bq    = (const float*)d_in[4];
    const float* Wv    = (const float*)d_in[5];
    const float* bv    = (const float*)d_in[6];
    float* out = (float*)d_out;

    int N_ = in_sizes[0] / HID;
    int E_ = in_sizes[1] / 2;

    // workspace: P (bf16 N_*32) | Q (bf16 N_*32) | Wfrag (bf16 64*128) | bias (f32 64)
    size_t need = (size_t)N_ * OUTW * 2 * sizeof(unsigned short)
                + (size_t)TOT * HID * sizeof(unsigned short)
                + TOT * sizeof(float);
    if (ws_size >= need) {
        unsigned short* P     = (unsigned short*)d_ws;
        unsigned short* Qb    = P + (size_t)N_ * OUTW;
        unsigned short* Wfrag = Qb + (size_t)N_ * OUTW;
        float*          bias  = (float*)(Wfrag + (size_t)TOT * HID);

        prep_bf16<<<(TOT * HID + 255) / 256, 256, 0, stream>>>(Wq, bq, Wv, bv, Wfrag, bias);
        proj_mfma<<<(N_ + 63) / 64, 256, 0, stream>>>(x, Wfrag, bias, P, Qb, N_);
        edge_bf16<<<(E_ + 255) / 256, 256, 0, stream>>>(e, P, Qb, ratio, out, E_);
    } else {
        fused_kernel<<<(E_ + 255) / 256, 256, 0, stream>>>(x, e, ratio, Wq, bq, Wv, bv, out, E_);
    }
}